// Round 5
// baseline (11496.643 us; speedup 1.0000x reference)
//
#include <hip/hip_runtime.h>
#include <stdint.h>

// LIIF fused inference for MI355X (gfx950).  ROUND 5 = MEASUREMENT ROUND.
// Real pipeline unchanged (v4). Two diagnostic kernels appended (write scratch only):
//   mlp_diag_gather   : geometry + h1pre gather + rel/relu + Xl writes, x16 reps.
//                       -> slowest dispatch class => its dur/occupancy/counters visible
//                          in rocprof top-5. Gather-phase cost per pass = dur/16.
//   mlp_diag_nogather : full v4 mlp with gather loads replaced by constants.
//                       -> cost = total_dur - 1166us - 16*G (subtraction channel).
//
// ws layout (42,631,168 bytes):
//   feat   bf16  [0,        8388608)   (also diag scratch sinks; conv1 rewrites fully)
//   h1_pre bf16  [8388608,  41943040)
//   w1pt   bf16  [41943040, 42237952)   [256][576]
//   w2t    bf16  [42237952, 42369024)   [256][256]
//   w3t    bf16  [42369024, 42500096)
//   w4t    bf16  [42500096, 42631168)

typedef unsigned short u16;
typedef __attribute__((ext_vector_type(8))) short   short8;
typedef __attribute__((ext_vector_type(8))) __bf16  bf16x8;
typedef __attribute__((ext_vector_type(4))) float   f32x4;

__device__ __forceinline__ float bf2f(u16 u) {
  union { uint32_t i; float f; } v; v.i = ((uint32_t)u) << 16; return v.f;
}
__device__ __forceinline__ u16 f2bf(float f) {
  union { float f; uint32_t i; } v; v.f = f;
  return (u16)((v.i + 0x7FFFu + ((v.i >> 16) & 1u)) >> 16);  // RNE; inputs finite
}

// ---------------------------------------------------------------- weights prep
__global__ void prep_weights(const float* __restrict__ w1, const float* __restrict__ w2,
                             const float* __restrict__ w3, const float* __restrict__ w4,
                             u16* __restrict__ w1pt, u16* __restrict__ w2t,
                             u16* __restrict__ w3t, u16* __restrict__ w4t) {
  int tid = blockIdx.x * 256 + threadIdx.x;
  const int N1 = 256 * 576;
  if (tid < N1) {
    int o = tid / 576, kk = tid - o * 576;
    int t = kk >> 6, c = kk & 63;               // k' = t*64 + c  <->  w1 row c*9+t
    w1pt[tid] = f2bf(w1[(c * 9 + t) * 256 + o]);
  } else {
    int u = tid - N1;
    if (u < 3 * 65536) {
      int layer = u >> 16, r = u & 65535;
      int o = r >> 8, k = r & 255;
      const float* src = (layer == 0) ? w2 : (layer == 1) ? w3 : w4;
      u16* dst = (layer == 0) ? w2t : (layer == 1) ? w3t : w4t;
      dst[o * 256 + k] = f2bf(src[k * 256 + o]);
    }
  }
}

// ---------------------------------------------------------------- conv 3x3, 1->64, channel-last out
__global__ void conv1_kernel(const float* __restrict__ inp, const float* __restrict__ cw,
                             const float* __restrict__ cb, u16* __restrict__ feat) {
  int tid = blockIdx.x * 256 + threadIdx.x;     // ((b*128+y)*128+x)*64 + c
  int c = tid & 63;
  int x = (tid >> 6) & 127;
  int y = (tid >> 13) & 127;
  int b = tid >> 20;
  const float* ip = inp + b * 16384;
  float s = cb[c];
  #pragma unroll
  for (int kh = 0; kh < 3; ++kh) {
    int iy = y + kh - 1;
    if (iy < 0 || iy > 127) continue;
    #pragma unroll
    for (int kw = 0; kw < 3; ++kw) {
      int ix = x + kw - 1;
      if (ix < 0 || ix > 127) continue;
      s += ip[iy * 128 + ix] * cw[c * 9 + kh * 3 + kw];
    }
  }
  feat[tid] = f2bf(s);
}

// ---------------------------------------------------------------- layer 1 as 3x3 conv-GEMM
__global__ __launch_bounds__(256) void layer1_kernel(const u16* __restrict__ feat,
                                                     const u16* __restrict__ w1pt,
                                                     const float* __restrict__ b1,
                                                     u16* __restrict__ h1pre) {
  __shared__ short Al[64 * 40];
  __shared__ short Wl[256 * 40];

  int tid = threadIdx.x;
  int lane = tid & 63, wave = tid >> 6;
  int bid = blockIdx.x;
  int b = bid >> 8, rem = bid & 255;
  int y = rem >> 1, x0 = (rem & 1) << 6;

  f32x4 acc[4][4];
  #pragma unroll
  for (int i = 0; i < 4; ++i)
    #pragma unroll
    for (int j = 0; j < 4; ++j) acc[i][j] = (f32x4){0.f, 0.f, 0.f, 0.f};

  int apx = tid >> 2, acq = tid & 3;

  for (int kt = 0; kt < 18; ++kt) {
    __syncthreads();
    {
      int t = kt >> 1, cbase = (kt & 1) << 5;
      int dh = t / 3 - 1, dw = t % 3 - 1;
      int yy = y + dh;
      int xx = x0 + apx + dw;
      short8 v = {0, 0, 0, 0, 0, 0, 0, 0};
      if (yy >= 0 && yy < 128 && xx >= 0 && xx < 128)
        v = *(const short8*)(feat + (((b * 128 + yy) * 128 + xx) * 64 + cbase + acq * 8));
      *(short8*)(Al + apx * 40 + acq * 8) = v;
    }
    {
      #pragma unroll
      for (int it = 0; it < 5; ++it) {
        int ch = it * 256 + tid;
        int o = ch / 5, j = ch - o * 5;
        if (j < 4) {
          short8 v = *(const short8*)(w1pt + (o * 576 + kt * 32 + j * 8));
          *(short8*)(Wl + o * 40 + j * 8) = v;
        }
      }
    }
    __syncthreads();
    int g = lane >> 4, l15 = lane & 15;
    bf16x8 a[4];
    #pragma unroll
    for (int mf = 0; mf < 4; ++mf)
      a[mf] = *(const bf16x8*)(Al + (mf * 16 + l15) * 40 + g * 8);
    int wc0 = wave * 64;
    #pragma unroll
    for (int nf = 0; nf < 4; ++nf) {
      bf16x8 bfr = *(const bf16x8*)(Wl + (wc0 + nf * 16 + l15) * 40 + g * 8);
      #pragma unroll
      for (int mf = 0; mf < 4; ++mf)
        acc[mf][nf] = __builtin_amdgcn_mfma_f32_16x16x32_bf16(a[mf], bfr, acc[mf][nf], 0, 0, 0);
    }
  }

  int g = lane >> 4, l15 = lane & 15;
  int wc0 = wave * 64;
  #pragma unroll
  for (int nf = 0; nf < 4; ++nf) {
    int col = wc0 + nf * 16 + l15;
    float bias = b1[col];
    #pragma unroll
    for (int mf = 0; mf < 4; ++mf)
      #pragma unroll
      for (int i = 0; i < 4; ++i) {
        int px = mf * 16 + 4 * g + i;
        int pixel = y * 128 + x0 + px;
        h1pre[(((b << 14) + pixel) << 8) + col] = f2bf(acc[mf][nf][i] + bias);
      }
  }
}

// ---------------------------------------------------------------- fused per-query MLP v4 (real)
__global__ __launch_bounds__(256) void mlp_kernel(
    const float* __restrict__ coord, const float* __restrict__ cell,
    const u16* __restrict__ h1pre,
    const u16* __restrict__ w2t, const u16* __restrict__ w3t, const u16* __restrict__ w4t,
    const float* __restrict__ w1, const float* __restrict__ b2, const float* __restrict__ b3,
    const float* __restrict__ b4, const float* __restrict__ w5, const float* __restrict__ b5,
    float* __restrict__ out) {
  __shared__ short Xl[64 * 264];
  __shared__ float relv[64][4];
  __shared__ float area_l[64];
  __shared__ int   idx_l[64];
  __shared__ float predp[4][64];

  int tid = threadIdx.x;
  int lane = tid & 63, wave = tid >> 6;
  int g = lane >> 4, l15 = lane & 15;
  int wc0 = wave * 64;
  int bid = blockIdx.x;

  if (tid < 64) {
    int t = tid >> 2, br = tid & 3;
    int gq = bid * 16 + t;
    int b = gq / 30000;
    float c0 = coord[gq * 2 + 0];
    float c1 = coord[gq * 2 + 1];
    float ce0 = cell[gq * 2 + 0];
    float ce1 = cell[gq * 2 + 1];
    float vx = (br & 2) ? 1.0f : -1.0f;
    float vy = (br & 1) ? 1.0f : -1.0f;
    float s0 = c0 + vx * (1.0f / 128.0f) + 1e-6f;
    float s1 = c1 + vy * (1.0f / 128.0f) + 1e-6f;
    s0 = fminf(fmaxf(s0, -1.0f + 1e-6f), 1.0f - 1e-6f);
    s1 = fminf(fmaxf(s1, -1.0f + 1e-6f), 1.0f - 1e-6f);
    float fi = rintf((s0 + 1.0f) * 64.0f - 0.5f);
    float fj = rintf((s1 + 1.0f) * 64.0f - 0.5f);
    fi = fminf(fmaxf(fi, 0.0f), 127.0f);
    fj = fminf(fmaxf(fj, 0.0f), 127.0f);
    float qy = -1.0f + (2.0f * fi + 1.0f) / 128.0f;
    float qx = -1.0f + (2.0f * fj + 1.0f) / 128.0f;
    float rel0 = (c0 - qy) * 128.0f;
    float rel1 = (c1 - qx) * 128.0f;
    idx_l[tid] = (b << 14) + (int)fi * 128 + (int)fj;
    relv[tid][0] = rel0;
    relv[tid][1] = rel1;
    relv[tid][2] = ce0 * 128.0f;
    relv[tid][3] = ce1 * 128.0f;
    area_l[tid] = fabsf(rel0 * rel1) + 1e-9f;
  }
  __syncthreads();

  {
    const float* wr = w1 + 576 * 256;
    short8 v[8];
    #pragma unroll
    for (int it = 0; it < 8; ++it) {
      int ch = it * 256 + tid;
      int row = ch >> 5, c16 = ch & 31;
      v[it] = *(const short8*)(h1pre + ((size_t)idx_l[row] << 8) + c16 * 8);
    }
    #pragma unroll
    for (int it = 0; it < 8; ++it) {
      int ch = it * 256 + tid;
      int row = ch >> 5, c16 = ch & 31;
      float r0 = relv[row][0], r1 = relv[row][1], r2 = relv[row][2], r3 = relv[row][3];
      short8 xo;
      #pragma unroll
      for (int e = 0; e < 8; ++e) {
        int col = c16 * 8 + e;
        float val = bf2f((u16)v[it][e]) + r0 * wr[col] + r1 * wr[256 + col] +
                    r2 * wr[512 + col] + r3 * wr[768 + col];
        xo[e] = (short)f2bf(fmaxf(val, 0.0f));
      }
      *(short8*)(Xl + row * 264 + c16 * 8) = xo;
    }
  }
  __syncthreads();

  const u16* Wgs[3] = {w2t, w3t, w4t};
  const float* Bgs[3] = {b2, b3, b4};
  f32x4 acc[4][4];

  #pragma unroll
  for (int layer = 0; layer < 3; ++layer) {
    const u16* Wg = Wgs[layer];
    #pragma unroll
    for (int mf = 0; mf < 4; ++mf)
      #pragma unroll
      for (int nf = 0; nf < 4; ++nf) acc[mf][nf] = (f32x4){0.f, 0.f, 0.f, 0.f};

    bf16x8 breg[32];
    #pragma unroll
    for (int ks = 0; ks < 8; ++ks)
      #pragma unroll
      for (int nf = 0; nf < 4; ++nf)
        breg[ks * 4 + nf] =
            *(const bf16x8*)(Wg + (wc0 + nf * 16 + l15) * 256 + ks * 32 + g * 8);

    #pragma unroll
    for (int ks = 0; ks < 8; ++ks) {
      bf16x8 a[4];
      #pragma unroll
      for (int mf = 0; mf < 4; ++mf)
        a[mf] = *(const bf16x8*)(Xl + (mf * 16 + l15) * 264 + ks * 32 + g * 8);
      #pragma unroll
      for (int nf = 0; nf < 4; ++nf)
        #pragma unroll
        for (int mf = 0; mf < 4; ++mf)
          acc[mf][nf] =
              __builtin_amdgcn_mfma_f32_16x16x32_bf16(a[mf], breg[ks * 4 + nf], acc[mf][nf], 0, 0, 0);
    }

    const float* bias = Bgs[layer];
    __syncthreads();
    if (layer < 2) {
      #pragma unroll
      for (int nf = 0; nf < 4; ++nf) {
        int col = wc0 + nf * 16 + l15;
        float bv = bias[col];
        #pragma unroll
        for (int mf = 0; mf < 4; ++mf)
          #pragma unroll
          for (int i = 0; i < 4; ++i) {
            float v = fmaxf(acc[mf][nf][i] + bv, 0.0f);
            Xl[(mf * 16 + 4 * g + i) * 264 + col] = (short)f2bf(v);
          }
      }
      __syncthreads();
    } else {
      float s[4][4];
      #pragma unroll
      for (int mf = 0; mf < 4; ++mf)
        #pragma unroll
        for (int i = 0; i < 4; ++i) s[mf][i] = 0.0f;
      #pragma unroll
      for (int nf = 0; nf < 4; ++nf) {
        int col = wc0 + nf * 16 + l15;
        float bv = bias[col];
        float wv = w5[col];
        #pragma unroll
        for (int mf = 0; mf < 4; ++mf)
          #pragma unroll
          for (int i = 0; i < 4; ++i)
            s[mf][i] += fmaxf(acc[mf][nf][i] + bv, 0.0f) * wv;
      }
      #pragma unroll
      for (int d = 1; d < 16; d <<= 1)
        #pragma unroll
        for (int mf = 0; mf < 4; ++mf)
          #pragma unroll
          for (int i = 0; i < 4; ++i)
            s[mf][i] += __shfl_xor(s[mf][i], d, 64);
      if (l15 == 0) {
        #pragma unroll
        for (int mf = 0; mf < 4; ++mf)
          #pragma unroll
          for (int i = 0; i < 4; ++i)
            predp[wave][mf * 16 + 4 * g + i] = s[mf][i];
      }
    }
  }
  __syncthreads();

  if (tid < 16) {
    int gq = bid * 16 + tid;
    float pr[4], ar[4];
    #pragma unroll
    for (int br = 0; br < 4; ++br) {
      int r = tid * 4 + br;
      pr[br] = predp[0][r] + predp[1][r] + predp[2][r] + predp[3][r] + b5[0];
      ar[br] = area_l[r];
    }
    float tot = ar[0] + ar[1] + ar[2] + ar[3];
    float ret = 0.0f;
    #pragma unroll
    for (int br = 0; br < 4; ++br) ret += pr[br] * (ar[3 - br] / tot);
    out[gq] = ret;
  }
}

// ---------------------------------------------------------------- DIAG 1: gather-only, x16 reps
// Measures: geometry + scattered h1pre gather + rel/relu VALU + Xl LDS writes.
// dur/16 = per-pass gather-phase cost. Counters (occupancy, VALUBusy, hbm) readable in top-5.
__global__ __launch_bounds__(256) void mlp_diag_gather(
    const float* __restrict__ coord, const float* __restrict__ cell,
    const u16* __restrict__ h1pre, const float* __restrict__ w1,
    float* __restrict__ dout) {
  __shared__ short Xl[64 * 264];
  __shared__ float relv[64][4];
  __shared__ int   idx_l[64];

  int tid = threadIdx.x;
  int bid = blockIdx.x;
  float chk = 0.0f;

  for (int rep = 0; rep < 16; ++rep) {
    asm volatile("" ::: "memory");   // force re-load each rep (defeat CSE/hoist)
    __syncthreads();                 // prev-rep Xl readers done
    if (tid < 64) {
      int t = tid >> 2, br = tid & 3;
      int gq = bid * 16 + t;
      int b = gq / 30000;
      float c0 = coord[gq * 2 + 0];
      float c1 = coord[gq * 2 + 1];
      float ce0 = cell[gq * 2 + 0];
      float ce1 = cell[gq * 2 + 1];
      float vx = (br & 2) ? 1.0f : -1.0f;
      float vy = (br & 1) ? 1.0f : -1.0f;
      float s0 = c0 + vx * (1.0f / 128.0f) + 1e-6f;
      float s1 = c1 + vy * (1.0f / 128.0f) + 1e-6f;
      s0 = fminf(fmaxf(s0, -1.0f + 1e-6f), 1.0f - 1e-6f);
      s1 = fminf(fmaxf(s1, -1.0f + 1e-6f), 1.0f - 1e-6f);
      float fi = rintf((s0 + 1.0f) * 64.0f - 0.5f);
      float fj = rintf((s1 + 1.0f) * 64.0f - 0.5f);
      fi = fminf(fmaxf(fi, 0.0f), 127.0f);
      fj = fminf(fmaxf(fj, 0.0f), 127.0f);
      float qy = -1.0f + (2.0f * fi + 1.0f) / 128.0f;
      float qx = -1.0f + (2.0f * fj + 1.0f) / 128.0f;
      idx_l[tid] = (b << 14) + (int)fi * 128 + (int)fj;
      relv[tid][0] = (c0 - qy) * 128.0f;
      relv[tid][1] = (c1 - qx) * 128.0f;
      relv[tid][2] = ce0 * 128.0f;
      relv[tid][3] = ce1 * 128.0f;
    }
    __syncthreads();

    const float* wr = w1 + 576 * 256;
    short8 v[8];
    #pragma unroll
    for (int it = 0; it < 8; ++it) {
      int ch = it * 256 + tid;
      int row = ch >> 5, c16 = ch & 31;
      v[it] = *(const short8*)(h1pre + ((size_t)idx_l[row] << 8) + c16 * 8);
    }
    #pragma unroll
    for (int it = 0; it < 8; ++it) {
      int ch = it * 256 + tid;
      int row = ch >> 5, c16 = ch & 31;
      float r0 = relv[row][0], r1 = relv[row][1], r2 = relv[row][2], r3 = relv[row][3];
      short8 xo;
      #pragma unroll
      for (int e = 0; e < 8; ++e) {
        int col = c16 * 8 + e;
        float val = bf2f((u16)v[it][e]) + r0 * wr[col] + r1 * wr[256 + col] +
                    r2 * wr[512 + col] + r3 * wr[768 + col];
        xo[e] = (short)f2bf(fmaxf(val, 0.0f));
      }
      *(short8*)(Xl + row * 264 + c16 * 8) = xo;
    }
    __syncthreads();
    chk += (float)Xl[(tid * 131 + rep * 997) & 16383];  // keep Xl (and gather) live
  }
  asm volatile("" :: "v"(chk));
  if (tid == 0) dout[bid] = chk;
}

// ---------------------------------------------------------------- DIAG 2: full mlp minus gather
// Identical to mlp_kernel but gather loads replaced by constant bf16(1.0); writes scratch.
__global__ __launch_bounds__(256) void mlp_diag_nogather(
    const float* __restrict__ coord, const float* __restrict__ cell,
    const u16* __restrict__ w2t, const u16* __restrict__ w3t, const u16* __restrict__ w4t,
    const float* __restrict__ w1, const float* __restrict__ b2, const float* __restrict__ b3,
    const float* __restrict__ b4, const float* __restrict__ w5, const float* __restrict__ b5,
    float* __restrict__ dout) {
  __shared__ short Xl[64 * 264];
  __shared__ float relv[64][4];
  __shared__ float area_l[64];
  __shared__ float predp[4][64];

  int tid = threadIdx.x;
  int lane = tid & 63, wave = tid >> 6;
  int g = lane >> 4, l15 = lane & 15;
  int wc0 = wave * 64;
  int bid = blockIdx.x;

  if (tid < 64) {
    int t = tid >> 2, br = tid & 3;
    int gq = bid * 16 + t;
    float c0 = coord[gq * 2 + 0];
    float c1 = coord[gq * 2 + 1];
    float ce0 = cell[gq * 2 + 0];
    float ce1 = cell[gq * 2 + 1];
    float vx = (br & 2) ? 1.0f : -1.0f;
    float vy = (br & 1) ? 1.0f : -1.0f;
    float s0 = c0 + vx * (1.0f / 128.0f) + 1e-6f;
    float s1 = c1 + vy * (1.0f / 128.0f) + 1e-6f;
    s0 = fminf(fmaxf(s0, -1.0f + 1e-6f), 1.0f - 1e-6f);
    s1 = fminf(fmaxf(s1, -1.0f + 1e-6f), 1.0f - 1e-6f);
    float fi = rintf((s0 + 1.0f) * 64.0f - 0.5f);
    float fj = rintf((s1 + 1.0f) * 64.0f - 0.5f);
    fi = fminf(fmaxf(fi, 0.0f), 127.0f);
    fj = fminf(fmaxf(fj, 0.0f), 127.0f);
    float qy = -1.0f + (2.0f * fi + 1.0f) / 128.0f;
    float qx = -1.0f + (2.0f * fj + 1.0f) / 128.0f;
    float rel0 = (c0 - qy) * 128.0f;
    float rel1 = (c1 - qx) * 128.0f;
    relv[tid][0] = rel0;
    relv[tid][1] = rel1;
    relv[tid][2] = ce0 * 128.0f;
    relv[tid][3] = ce1 * 128.0f;
    area_l[tid] = fabsf(rel0 * rel1) + 1e-9f;
  }
  __syncthreads();

  {
    const float* wr = w1 + 576 * 256;
    #pragma unroll
    for (int it = 0; it < 8; ++it) {
      int ch = it * 256 + tid;
      int row = ch >> 5, c16 = ch & 31;
      float r0 = relv[row][0], r1 = relv[row][1], r2 = relv[row][2], r3 = relv[row][3];
      short8 xo;
      #pragma unroll
      for (int e = 0; e < 8; ++e) {
        int col = c16 * 8 + e;
        float val = 1.0f + r0 * wr[col] + r1 * wr[256 + col] +
                    r2 * wr[512 + col] + r3 * wr[768 + col];   // gather -> const 1.0
        xo[e] = (short)f2bf(fmaxf(val, 0.0f));
      }
      *(short8*)(Xl + row * 264 + c16 * 8) = xo;
    }
  }
  __syncthreads();

  const u16* Wgs[3] = {w2t, w3t, w4t};
  const float* Bgs[3] = {b2, b3, b4};
  f32x4 acc[4][4];

  #pragma unroll
  for (int layer = 0; layer < 3; ++layer) {
    const u16* Wg = Wgs[layer];
    #pragma unroll
    for (int mf = 0; mf < 4; ++mf)
      #pragma unroll
      for (int nf = 0; nf < 4; ++nf) acc[mf][nf] = (f32x4){0.f, 0.f, 0.f, 0.f};

    bf16x8 breg[32];
    #pragma unroll
    for (int ks = 0; ks < 8; ++ks)
      #pragma unroll
      for (int nf = 0; nf < 4; ++nf)
        breg[ks * 4 + nf] =
            *(const bf16x8*)(Wg + (wc0 + nf * 16 + l15) * 256 + ks * 32 + g * 8);

    #pragma unroll
    for (int ks = 0; ks < 8; ++ks) {
      bf16x8 a[4];
      #pragma unroll
      for (int mf = 0; mf < 4; ++mf)
        a[mf] = *(const bf16x8*)(Xl + (mf * 16 + l15) * 264 + ks * 32 + g * 8);
      #pragma unroll
      for (int nf = 0; nf < 4; ++nf)
        #pragma unroll
        for (int mf = 0; mf < 4; ++mf)
          acc[mf][nf] =
              __builtin_amdgcn_mfma_f32_16x16x32_bf16(a[mf], breg[ks * 4 + nf], acc[mf][nf], 0, 0, 0);
    }

    const float* bias = Bgs[layer];
    __syncthreads();
    if (layer < 2) {
      #pragma unroll
      for (int nf = 0; nf < 4; ++nf) {
        int col = wc0 + nf * 16 + l15;
        float bv = bias[col];
        #pragma unroll
        for (int mf = 0; mf < 4; ++mf)
          #pragma unroll
          for (int i = 0; i < 4; ++i) {
            float v = fmaxf(acc[mf][nf][i] + bv, 0.0f);
            Xl[(mf * 16 + 4 * g + i) * 264 + col] = (short)f2bf(v);
          }
      }
      __syncthreads();
    } else {
      float s[4][4];
      #pragma unroll
      for (int mf = 0; mf < 4; ++mf)
        #pragma unroll
        for (int i = 0; i < 4; ++i) s[mf][i] = 0.0f;
      #pragma unroll
      for (int nf = 0; nf < 4; ++nf) {
        int col = wc0 + nf * 16 + l15;
        float bv = bias[col];
        float wv = w5[col];
        #pragma unroll
        for (int mf = 0; mf < 4; ++mf)
          #pragma unroll
          for (int i = 0; i < 4; ++i)
            s[mf][i] += fmaxf(acc[mf][nf][i] + bv, 0.0f) * wv;
      }
      #pragma unroll
      for (int d = 1; d < 16; d <<= 1)
        #pragma unroll
        for (int mf = 0; mf < 4; ++mf)
          #pragma unroll
          for (int i = 0; i < 4; ++i)
            s[mf][i] += __shfl_xor(s[mf][i], d, 64);
      if (l15 == 0) {
        #pragma unroll
        for (int mf = 0; mf < 4; ++mf)
          #pragma unroll
          for (int i = 0; i < 4; ++i)
            predp[wave][mf * 16 + 4 * g + i] = s[mf][i];
      }
    }
  }
  __syncthreads();

  if (tid < 16) {
    float pr[4], ar[4];
    #pragma unroll
    for (int br = 0; br < 4; ++br) {
      int r = tid * 4 + br;
      pr[br] = predp[0][r] + predp[1][r] + predp[2][r] + predp[3][r] + b5[0];
      ar[br] = area_l[r];
    }
    float tot = ar[0] + ar[1] + ar[2] + ar[3];
    float ret = 0.0f;
    #pragma unroll
    for (int br = 0; br < 4; ++br) ret += pr[br] * (ar[3 - br] / tot);
    dout[bid * 16 + tid] = ret;
  }
}

// ---------------------------------------------------------------- launch
extern "C" void kernel_launch(void* const* d_in, const int* in_sizes, int n_in,
                              void* d_out, int out_size, void* d_ws, size_t ws_size,
                              hipStream_t stream) {
  const float* inp    = (const float*)d_in[0];
  const float* coord  = (const float*)d_in[1];
  const float* cell   = (const float*)d_in[2];
  const float* conv_w = (const float*)d_in[3];
  const float* conv_b = (const float*)d_in[4];
  const float* w1 = (const float*)d_in[5];
  const float* b1 = (const float*)d_in[6];
  const float* w2 = (const float*)d_in[7];
  const float* b2 = (const float*)d_in[8];
  const float* w3 = (const float*)d_in[9];
  const float* b3 = (const float*)d_in[10];
  const float* w4 = (const float*)d_in[11];
  const float* b4 = (const float*)d_in[12];
  const float* w5 = (const float*)d_in[13];
  const float* b5 = (const float*)d_in[14];
  float* out = (float*)d_out;

  char* ws = (char*)d_ws;
  u16* feat  = (u16*)(ws);
  u16* h1pre = (u16*)(ws + 8388608);
  u16* w1pt  = (u16*)(ws + 41943040);
  u16* w2t   = (u16*)(ws + 42237952);
  u16* w3t   = (u16*)(ws + 42369024);
  u16* w4t   = (u16*)(ws + 42500096);
  float* diag1 = (float*)(ws);             // within feat region; conv1 rewrites
  float* diag2 = (float*)(ws + 4194304);   // within feat region; conv1 rewrites

  hipLaunchKernelGGL(prep_weights, dim3(1344), dim3(256), 0, stream,
                     w1, w2, w3, w4, w1pt, w2t, w3t, w4t);
  hipLaunchKernelGGL(conv1_kernel, dim3(16384), dim3(256), 0, stream,
                     inp, conv_w, conv_b, feat);
  hipLaunchKernelGGL(layer1_kernel, dim3(1024), dim3(256), 0, stream,
                     feat, w1pt, b1, h1pre);
  hipLaunchKernelGGL(mlp_kernel, dim3(7500), dim3(256), 0, stream,
                     coord, cell, h1pre, w2t, w3t, w4t, w1, b2, b3, b4, w5, b5, out);
  // ---- diagnostics (scratch only; feat fully rewritten by conv1 next replay)
  hipLaunchKernelGGL(mlp_diag_gather, dim3(7500), dim3(256), 0, stream,
                     coord, cell, h1pre, w1, diag1);
  hipLaunchKernelGGL(mlp_diag_nogather, dim3(7500), dim3(256), 0, stream,
                     coord, cell, w2t, w3t, w4t, w1, b2, b3, b4, w5, b5, diag2);
}

// Round 6
// 431.502 us; speedup vs baseline: 26.6433x; 26.6433x over previous
//
#include <hip/hip_runtime.h>
#include <stdint.h>

// LIIF fused inference for MI355X (gfx950).
// B=4, C=64, H=W=128, Q=30000, HID=256, IN_DIM=580.
//
// v5 theory: per-block time ∝ exposed vector-mem instruction count (zero MLP at
// 1 wave/SIMD). Cut loads/row 4x and batch-issue the rest:
//   - wr rel-weight table (4x256 f32) -> LDS float4 table, loaded once per block.
//   - 2 tiles of 64 rows per block (128 rows, 32 queries): per-layer breg weight
//     preload (32x16B, sched_barrier-pinned batch) serves BOTH tiles' k-loops.
//   - gather: 8x16B batch per tile.
//
// ws layout (42,631,168 bytes):
//   feat   bf16  [0,        8388608)
//   h1_pre bf16  [8388608,  41943040)
//   w1pt   bf16  [41943040, 42237952)   [256][576]
//   w2t    bf16  [42237952, 42369024)   [256][256]  (w2t[o][k] = w2[k][o])
//   w3t    bf16  [42369024, 42500096)
//   w4t    bf16  [42500096, 42631168)

typedef unsigned short u16;
typedef __attribute__((ext_vector_type(8))) short   short8;
typedef __attribute__((ext_vector_type(8))) __bf16  bf16x8;
typedef __attribute__((ext_vector_type(4))) float   f32x4;

__device__ __forceinline__ float bf2f(u16 u) {
  union { uint32_t i; float f; } v; v.i = ((uint32_t)u) << 16; return v.f;
}
__device__ __forceinline__ u16 f2bf(float f) {
  union { float f; uint32_t i; } v; v.f = f;
  return (u16)((v.i + 0x7FFFu + ((v.i >> 16) & 1u)) >> 16);  // RNE; inputs finite
}

// ---------------------------------------------------------------- weights prep
__global__ void prep_weights(const float* __restrict__ w1, const float* __restrict__ w2,
                             const float* __restrict__ w3, const float* __restrict__ w4,
                             u16* __restrict__ w1pt, u16* __restrict__ w2t,
                             u16* __restrict__ w3t, u16* __restrict__ w4t) {
  int tid = blockIdx.x * 256 + threadIdx.x;
  const int N1 = 256 * 576;
  if (tid < N1) {
    int o = tid / 576, kk = tid - o * 576;
    int t = kk >> 6, c = kk & 63;               // k' = t*64 + c  <->  w1 row c*9+t
    w1pt[tid] = f2bf(w1[(c * 9 + t) * 256 + o]);
  } else {
    int u = tid - N1;
    if (u < 3 * 65536) {
      int layer = u >> 16, r = u & 65535;
      int o = r >> 8, k = r & 255;
      const float* src = (layer == 0) ? w2 : (layer == 1) ? w3 : w4;
      u16* dst = (layer == 0) ? w2t : (layer == 1) ? w3t : w4t;
      dst[o * 256 + k] = f2bf(src[k * 256 + o]);
    }
  }
}

// ---------------------------------------------------------------- conv 3x3, 1->64, channel-last out
__global__ void conv1_kernel(const float* __restrict__ inp, const float* __restrict__ cw,
                             const float* __restrict__ cb, u16* __restrict__ feat) {
  int tid = blockIdx.x * 256 + threadIdx.x;     // ((b*128+y)*128+x)*64 + c
  int c = tid & 63;
  int x = (tid >> 6) & 127;
  int y = (tid >> 13) & 127;
  int b = tid >> 20;
  const float* ip = inp + b * 16384;
  float s = cb[c];
  #pragma unroll
  for (int kh = 0; kh < 3; ++kh) {
    int iy = y + kh - 1;
    if (iy < 0 || iy > 127) continue;
    #pragma unroll
    for (int kw = 0; kw < 3; ++kw) {
      int ix = x + kw - 1;
      if (ix < 0 || ix > 127) continue;
      s += ip[iy * 128 + ix] * cw[c * 9 + kh * 3 + kw];
    }
  }
  feat[tid] = f2bf(s);
}

// ---------------------------------------------------------------- layer 1 as 3x3 conv-GEMM
__global__ __launch_bounds__(256) void layer1_kernel(const u16* __restrict__ feat,
                                                     const u16* __restrict__ w1pt,
                                                     const float* __restrict__ b1,
                                                     u16* __restrict__ h1pre) {
  __shared__ short Al[64 * 40];
  __shared__ short Wl[256 * 40];

  int tid = threadIdx.x;
  int lane = tid & 63, wave = tid >> 6;
  int bid = blockIdx.x;
  int b = bid >> 8, rem = bid & 255;
  int y = rem >> 1, x0 = (rem & 1) << 6;

  f32x4 acc[4][4];
  #pragma unroll
  for (int i = 0; i < 4; ++i)
    #pragma unroll
    for (int j = 0; j < 4; ++j) acc[i][j] = (f32x4){0.f, 0.f, 0.f, 0.f};

  int apx = tid >> 2, acq = tid & 3;

  for (int kt = 0; kt < 18; ++kt) {
    __syncthreads();
    {
      int t = kt >> 1, cbase = (kt & 1) << 5;
      int dh = t / 3 - 1, dw = t % 3 - 1;
      int yy = y + dh;
      int xx = x0 + apx + dw;
      short8 v = {0, 0, 0, 0, 0, 0, 0, 0};
      if (yy >= 0 && yy < 128 && xx >= 0 && xx < 128)
        v = *(const short8*)(feat + (((b * 128 + yy) * 128 + xx) * 64 + cbase + acq * 8));
      *(short8*)(Al + apx * 40 + acq * 8) = v;
    }
    {
      #pragma unroll
      for (int it = 0; it < 5; ++it) {
        int ch = it * 256 + tid;
        int o = ch / 5, j = ch - o * 5;
        if (j < 4) {
          short8 v = *(const short8*)(w1pt + (o * 576 + kt * 32 + j * 8));
          *(short8*)(Wl + o * 40 + j * 8) = v;
        }
      }
    }
    __syncthreads();
    int g = lane >> 4, l15 = lane & 15;
    bf16x8 a[4];
    #pragma unroll
    for (int mf = 0; mf < 4; ++mf)
      a[mf] = *(const bf16x8*)(Al + (mf * 16 + l15) * 40 + g * 8);
    int wc0 = wave * 64;
    #pragma unroll
    for (int nf = 0; nf < 4; ++nf) {
      bf16x8 bfr = *(const bf16x8*)(Wl + (wc0 + nf * 16 + l15) * 40 + g * 8);
      #pragma unroll
      for (int mf = 0; mf < 4; ++mf)
        acc[mf][nf] = __builtin_amdgcn_mfma_f32_16x16x32_bf16(a[mf], bfr, acc[mf][nf], 0, 0, 0);
    }
  }

  int g = lane >> 4, l15 = lane & 15;
  int wc0 = wave * 64;
  #pragma unroll
  for (int nf = 0; nf < 4; ++nf) {
    int col = wc0 + nf * 16 + l15;
    float bias = b1[col];
    #pragma unroll
    for (int mf = 0; mf < 4; ++mf)
      #pragma unroll
      for (int i = 0; i < 4; ++i) {
        int px = mf * 16 + 4 * g + i;
        int pixel = y * 128 + x0 + px;
        h1pre[(((b << 14) + pixel) << 8) + col] = f2bf(acc[mf][nf][i] + bias);
      }
  }
}

// ---------------------------------------------------------------- fused per-query MLP v5
// 256 thr / 4 waves. 2 tiles x 64 rows = 128 rows (32 queries) per block; 3750 blocks.
// Per layer: ONE batched breg preload (32x16B) serves both tiles' pure-LDS k-loops.
// wr rel-table in LDS as float4[256]. launch_bounds(256,2): VGPR<=256, 2 blocks/CU.
__global__ __launch_bounds__(256, 2) void mlp_kernel(
    const float* __restrict__ coord, const float* __restrict__ cell,
    const u16* __restrict__ h1pre,
    const u16* __restrict__ w2t, const u16* __restrict__ w3t, const u16* __restrict__ w4t,
    const float* __restrict__ w1, const float* __restrict__ b2, const float* __restrict__ b3,
    const float* __restrict__ b4, const float* __restrict__ w5, const float* __restrict__ b5,
    float* __restrict__ out) {
  __shared__ short Xl[2][64 * 264];  // [tile][row*264+k], rows padded 256->264
  __shared__ float wrl[256 * 4];     // [col][4]: w1 rel rows as float4 per col
  __shared__ float relv[128][4];
  __shared__ float area_l[128];
  __shared__ int   idx_l[128];       // (b<<14) + pixel
  __shared__ float predp[4][128];

  int tid = threadIdx.x;
  int lane = tid & 63, wave = tid >> 6;
  int g = lane >> 4, l15 = lane & 15;
  int wc0 = wave * 64;
  int bid = blockIdx.x;              // 3750 blocks x 32 queries

  // ---- wr table -> LDS (one coalesced batch: 4 floats/thread)
  {
    const float* wr = w1 + 576 * 256;   // [4][256] fp32
    #pragma unroll
    for (int a = 0; a < 4; ++a) wrl[tid * 4 + a] = wr[a * 256 + tid];
  }

  // ---- geometry for all 128 rows in one pass
  if (tid < 128) {
    int t = tid >> 2, br = tid & 3;            // branch order: vx outer, vy inner
    int gq = bid * 32 + t;
    int b = gq / 30000;
    float c0 = coord[gq * 2 + 0];
    float c1 = coord[gq * 2 + 1];
    float ce0 = cell[gq * 2 + 0];
    float ce1 = cell[gq * 2 + 1];
    float vx = (br & 2) ? 1.0f : -1.0f;
    float vy = (br & 1) ? 1.0f : -1.0f;
    float s0 = c0 + vx * (1.0f / 128.0f) + 1e-6f;
    float s1 = c1 + vy * (1.0f / 128.0f) + 1e-6f;
    s0 = fminf(fmaxf(s0, -1.0f + 1e-6f), 1.0f - 1e-6f);
    s1 = fminf(fmaxf(s1, -1.0f + 1e-6f), 1.0f - 1e-6f);
    float fi = rintf((s0 + 1.0f) * 64.0f - 0.5f);
    float fj = rintf((s1 + 1.0f) * 64.0f - 0.5f);
    fi = fminf(fmaxf(fi, 0.0f), 127.0f);
    fj = fminf(fmaxf(fj, 0.0f), 127.0f);
    float qy = -1.0f + (2.0f * fi + 1.0f) / 128.0f;
    float qx = -1.0f + (2.0f * fj + 1.0f) / 128.0f;
    float rel0 = (c0 - qy) * 128.0f;
    float rel1 = (c1 - qx) * 128.0f;
    idx_l[tid] = (b << 14) + (int)fi * 128 + (int)fj;
    relv[tid][0] = rel0;
    relv[tid][1] = rel1;
    relv[tid][2] = ce0 * 128.0f;
    relv[tid][3] = ce1 * 128.0f;
    area_l[tid] = fabsf(rel0 * rel1) + 1e-9f;
  }
  __syncthreads();

  // ---- gather: per tile, one batch of 8x16B loads, then process -> Xl[t]
  #pragma unroll
  for (int t = 0; t < 2; ++t) {
    short8 v[8];
    #pragma unroll
    for (int it = 0; it < 8; ++it) {
      int ch = it * 256 + tid;        // 2048 chunks: 64 rows x 32 x 16B
      int rl = ch >> 5, c16 = ch & 31;
      v[it] = *(const short8*)(h1pre + ((size_t)idx_l[t * 64 + rl] << 8) + c16 * 8);
    }
    __builtin_amdgcn_sched_barrier(0);  // keep the 8 loads batched
    #pragma unroll
    for (int it = 0; it < 8; ++it) {
      int ch = it * 256 + tid;
      int rl = ch >> 5, c16 = ch & 31;
      int row = t * 64 + rl;
      float r0 = relv[row][0], r1 = relv[row][1], r2 = relv[row][2], r3 = relv[row][3];
      short8 xo;
      #pragma unroll
      for (int e = 0; e < 8; ++e) {
        int col = c16 * 8 + e;
        f32x4 wv = *(const f32x4*)(wrl + col * 4);
        float val = bf2f((u16)v[it][e]) + r0 * wv[0] + r1 * wv[1] + r2 * wv[2] + r3 * wv[3];
        xo[e] = (short)f2bf(fmaxf(val, 0.0f));
      }
      *(short8*)(&Xl[t][rl * 264 + c16 * 8]) = xo;
    }
  }
  __syncthreads();

  const u16* Wgs[3] = {w2t, w3t, w4t};
  const float* Bgs[3] = {b2, b3, b4};

  #pragma unroll
  for (int layer = 0; layer < 3; ++layer) {
    const u16* Wg = Wgs[layer];
    const float* bias = Bgs[layer];

    // ONE batched weight preload per layer (serves both tiles)
    bf16x8 breg[32];
    #pragma unroll
    for (int ks = 0; ks < 8; ++ks)
      #pragma unroll
      for (int nf = 0; nf < 4; ++nf)
        breg[ks * 4 + nf] =
            *(const bf16x8*)(Wg + (wc0 + nf * 16 + l15) * 256 + ks * 32 + g * 8);
    __builtin_amdgcn_sched_barrier(0);  // pin the 32 loads as one batch

    #pragma unroll
    for (int t = 0; t < 2; ++t) {
      f32x4 acc[4][4];
      #pragma unroll
      for (int mf = 0; mf < 4; ++mf)
        #pragma unroll
        for (int nf = 0; nf < 4; ++nf) acc[mf][nf] = (f32x4){0.f, 0.f, 0.f, 0.f};

      #pragma unroll
      for (int ks = 0; ks < 8; ++ks) {
        bf16x8 a[4];
        #pragma unroll
        for (int mf = 0; mf < 4; ++mf)
          a[mf] = *(const bf16x8*)(&Xl[t][(mf * 16 + l15) * 264 + ks * 32 + g * 8]);
        #pragma unroll
        for (int nf = 0; nf < 4; ++nf)
          #pragma unroll
          for (int mf = 0; mf < 4; ++mf)
            acc[mf][nf] =
                __builtin_amdgcn_mfma_f32_16x16x32_bf16(a[mf], breg[ks * 4 + nf], acc[mf][nf], 0, 0, 0);
      }

      __syncthreads();   // all waves done READING Xl[t] before overwrite
      if (layer < 2) {
        #pragma unroll
        for (int nf = 0; nf < 4; ++nf) {
          int col = wc0 + nf * 16 + l15;
          float bv = bias[col];
          #pragma unroll
          for (int mf = 0; mf < 4; ++mf)
            #pragma unroll
            for (int i = 0; i < 4; ++i) {
              float v = fmaxf(acc[mf][nf][i] + bv, 0.0f);
              Xl[t][(mf * 16 + 4 * g + i) * 264 + col] = (short)f2bf(v);
            }
        }
      } else {
        // head: relu(acc+b4) dot w5, reduce across 16-lane col group
        float s[4][4];
        #pragma unroll
        for (int mf = 0; mf < 4; ++mf)
          #pragma unroll
          for (int i = 0; i < 4; ++i) s[mf][i] = 0.0f;
        #pragma unroll
        for (int nf = 0; nf < 4; ++nf) {
          int col = wc0 + nf * 16 + l15;
          float bv = bias[col];
          float wv = w5[col];
          #pragma unroll
          for (int mf = 0; mf < 4; ++mf)
            #pragma unroll
            for (int i = 0; i < 4; ++i)
              s[mf][i] += fmaxf(acc[mf][nf][i] + bv, 0.0f) * wv;
        }
        #pragma unroll
        for (int d = 1; d < 16; d <<= 1)
          #pragma unroll
          for (int mf = 0; mf < 4; ++mf)
            #pragma unroll
            for (int i = 0; i < 4; ++i)
              s[mf][i] += __shfl_xor(s[mf][i], d, 64);
        if (l15 == 0) {
          #pragma unroll
          for (int mf = 0; mf < 4; ++mf)
            #pragma unroll
            for (int i = 0; i < 4; ++i)
              predp[wave][t * 64 + mf * 16 + 4 * g + i] = s[mf][i];
        }
      }
    }
    __syncthreads();   // epi(t1) complete before next layer / output
  }

  // ---- local ensemble (areas diagonally swapped)
  if (tid < 32) {
    int gq = bid * 32 + tid;
    float pr[4], ar[4];
    #pragma unroll
    for (int br = 0; br < 4; ++br) {
      int r = tid * 4 + br;
      pr[br] = predp[0][r] + predp[1][r] + predp[2][r] + predp[3][r] + b5[0];
      ar[br] = area_l[r];
    }
    float tot = ar[0] + ar[1] + ar[2] + ar[3];
    float ret = 0.0f;
    #pragma unroll
    for (int br = 0; br < 4; ++br) ret += pr[br] * (ar[3 - br] / tot);
    out[gq] = ret;
  }
}

// ---------------------------------------------------------------- launch
extern "C" void kernel_launch(void* const* d_in, const int* in_sizes, int n_in,
                              void* d_out, int out_size, void* d_ws, size_t ws_size,
                              hipStream_t stream) {
  const float* inp    = (const float*)d_in[0];
  const float* coord  = (const float*)d_in[1];
  const float* cell   = (const float*)d_in[2];
  const float* conv_w = (const float*)d_in[3];
  const float* conv_b = (const float*)d_in[4];
  const float* w1 = (const float*)d_in[5];
  const float* b1 = (const float*)d_in[6];
  const float* w2 = (const float*)d_in[7];
  const float* b2 = (const float*)d_in[8];
  const float* w3 = (const float*)d_in[9];
  const float* b3 = (const float*)d_in[10];
  const float* w4 = (const float*)d_in[11];
  const float* b4 = (const float*)d_in[12];
  const float* w5 = (const float*)d_in[13];
  const float* b5 = (const float*)d_in[14];
  float* out = (float*)d_out;

  char* ws = (char*)d_ws;
  u16* feat  = (u16*)(ws);
  u16* h1pre = (u16*)(ws + 8388608);
  u16* w1pt  = (u16*)(ws + 41943040);
  u16* w2t   = (u16*)(ws + 42237952);
  u16* w3t   = (u16*)(ws + 42369024);
  u16* w4t   = (u16*)(ws + 42500096);

  hipLaunchKernelGGL(prep_weights, dim3(1344), dim3(256), 0, stream,
                     w1, w2, w3, w4, w1pt, w2t, w3t, w4t);
  hipLaunchKernelGGL(conv1_kernel, dim3(16384), dim3(256), 0, stream,
                     inp, conv_w, conv_b, feat);
  hipLaunchKernelGGL(layer1_kernel, dim3(1024), dim3(256), 0, stream,
                     feat, w1pt, b1, h1pre);
  hipLaunchKernelGGL(mlp_kernel, dim3(3750), dim3(256), 0, stream,
                     coord, cell, h1pre, w2t, w3t, w4t, w1, b2, b3, b4, w5, b5, out);
}

// Round 7
// 397.900 us; speedup vs baseline: 28.8933x; 1.0844x over previous
//
#include <hip/hip_runtime.h>
#include <stdint.h>

// LIIF fused inference for MI355X (gfx950).
// B=4, C=64, H=W=128, Q=30000, HID=256, IN_DIM=580.
//
// v6: attack measured LDS conflicts (3.84e7) + VALU:
//   - operand-swapped MFMA (D[row=o][col=q]) -> epilogue writes are 16x ds_write_b64
//     (packed 4 consecutive hidden units) instead of 64x scalar b16; bias/w5 as float4.
//   - Xl XOR-swizzled (slot ^= row&7, 512B rows, no pad): conflict-free b128/b64.
//   - w1 rel-weight table in REGISTERS (c16=tid&31 is iteration-invariant) -- kills the
//     32-way-conflict f32x4 LDS reads (128/thread) of v5.
//   - bf16 convert via native __bf16 cast (cvt_pk) instead of 5-op manual RNE.
//
// ws layout (42,631,168 bytes):
//   feat   bf16  [0,        8388608)
//   h1_pre bf16  [8388608,  41943040)
//   w1pt   bf16  [41943040, 42237952)   [256][576]
//   w2t    bf16  [42237952, 42369024)   [256][256]  (w2t[o][k] = w2[k][o])
//   w3t    bf16  [42369024, 42500096)
//   w4t    bf16  [42500096, 42631168)

typedef unsigned short u16;
typedef __attribute__((ext_vector_type(8))) short   short8;
typedef __attribute__((ext_vector_type(8))) __bf16  bf16x8;
typedef __attribute__((ext_vector_type(4))) float   f32x4;

__device__ __forceinline__ float bf2f(u16 u) {
  union { uint32_t i; float f; } v; v.i = ((uint32_t)u) << 16; return v.f;
}
__device__ __forceinline__ u16 f2bf(float f) {            // manual RNE (cold kernels)
  union { float f; uint32_t i; } v; v.f = f;
  return (u16)((v.i + 0x7FFFu + ((v.i >> 16) & 1u)) >> 16);
}
__device__ __forceinline__ u16 bfbits(float f) {          // native cast (hot kernel)
  union { __bf16 h; u16 u; } c; c.h = (__bf16)f; return c.u;
}

// ---------------------------------------------------------------- weights prep
__global__ void prep_weights(const float* __restrict__ w1, const float* __restrict__ w2,
                             const float* __restrict__ w3, const float* __restrict__ w4,
                             u16* __restrict__ w1pt, u16* __restrict__ w2t,
                             u16* __restrict__ w3t, u16* __restrict__ w4t) {
  int tid = blockIdx.x * 256 + threadIdx.x;
  const int N1 = 256 * 576;
  if (tid < N1) {
    int o = tid / 576, kk = tid - o * 576;
    int t = kk >> 6, c = kk & 63;               // k' = t*64 + c  <->  w1 row c*9+t
    w1pt[tid] = f2bf(w1[(c * 9 + t) * 256 + o]);
  } else {
    int u = tid - N1;
    if (u < 3 * 65536) {
      int layer = u >> 16, r = u & 65535;
      int o = r >> 8, k = r & 255;
      const float* src = (layer == 0) ? w2 : (layer == 1) ? w3 : w4;
      u16* dst = (layer == 0) ? w2t : (layer == 1) ? w3t : w4t;
      dst[o * 256 + k] = f2bf(src[k * 256 + o]);
    }
  }
}

// ---------------------------------------------------------------- conv 3x3, 1->64, channel-last out
__global__ void conv1_kernel(const float* __restrict__ inp, const float* __restrict__ cw,
                             const float* __restrict__ cb, u16* __restrict__ feat) {
  int tid = blockIdx.x * 256 + threadIdx.x;     // ((b*128+y)*128+x)*64 + c
  int c = tid & 63;
  int x = (tid >> 6) & 127;
  int y = (tid >> 13) & 127;
  int b = tid >> 20;
  const float* ip = inp + b * 16384;
  float s = cb[c];
  #pragma unroll
  for (int kh = 0; kh < 3; ++kh) {
    int iy = y + kh - 1;
    if (iy < 0 || iy > 127) continue;
    #pragma unroll
    for (int kw = 0; kw < 3; ++kw) {
      int ix = x + kw - 1;
      if (ix < 0 || ix > 127) continue;
      s += ip[iy * 128 + ix] * cw[c * 9 + kh * 3 + kw];
    }
  }
  feat[tid] = f2bf(s);
}

// ---------------------------------------------------------------- layer 1 as 3x3 conv-GEMM
__global__ __launch_bounds__(256) void layer1_kernel(const u16* __restrict__ feat,
                                                     const u16* __restrict__ w1pt,
                                                     const float* __restrict__ b1,
                                                     u16* __restrict__ h1pre) {
  __shared__ short Al[64 * 40];
  __shared__ short Wl[256 * 40];

  int tid = threadIdx.x;
  int lane = tid & 63, wave = tid >> 6;
  int bid = blockIdx.x;
  int b = bid >> 8, rem = bid & 255;
  int y = rem >> 1, x0 = (rem & 1) << 6;

  f32x4 acc[4][4];
  #pragma unroll
  for (int i = 0; i < 4; ++i)
    #pragma unroll
    for (int j = 0; j < 4; ++j) acc[i][j] = (f32x4){0.f, 0.f, 0.f, 0.f};

  int apx = tid >> 2, acq = tid & 3;

  for (int kt = 0; kt < 18; ++kt) {
    __syncthreads();
    {
      int t = kt >> 1, cbase = (kt & 1) << 5;
      int dh = t / 3 - 1, dw = t % 3 - 1;
      int yy = y + dh;
      int xx = x0 + apx + dw;
      short8 v = {0, 0, 0, 0, 0, 0, 0, 0};
      if (yy >= 0 && yy < 128 && xx >= 0 && xx < 128)
        v = *(const short8*)(feat + (((b * 128 + yy) * 128 + xx) * 64 + cbase + acq * 8));
      *(short8*)(Al + apx * 40 + acq * 8) = v;
    }
    {
      #pragma unroll
      for (int it = 0; it < 5; ++it) {
        int ch = it * 256 + tid;
        int o = ch / 5, j = ch - o * 5;
        if (j < 4) {
          short8 v = *(const short8*)(w1pt + (o * 576 + kt * 32 + j * 8));
          *(short8*)(Wl + o * 40 + j * 8) = v;
        }
      }
    }
    __syncthreads();
    int g = lane >> 4, l15 = lane & 15;
    bf16x8 a[4];
    #pragma unroll
    for (int mf = 0; mf < 4; ++mf)
      a[mf] = *(const bf16x8*)(Al + (mf * 16 + l15) * 40 + g * 8);
    int wc0 = wave * 64;
    #pragma unroll
    for (int nf = 0; nf < 4; ++nf) {
      bf16x8 bfr = *(const bf16x8*)(Wl + (wc0 + nf * 16 + l15) * 40 + g * 8);
      #pragma unroll
      for (int mf = 0; mf < 4; ++mf)
        acc[mf][nf] = __builtin_amdgcn_mfma_f32_16x16x32_bf16(a[mf], bfr, acc[mf][nf], 0, 0, 0);
    }
  }

  int g = lane >> 4, l15 = lane & 15;
  int wc0 = wave * 64;
  #pragma unroll
  for (int nf = 0; nf < 4; ++nf) {
    int col = wc0 + nf * 16 + l15;
    float bias = b1[col];
    #pragma unroll
    for (int mf = 0; mf < 4; ++mf)
      #pragma unroll
      for (int i = 0; i < 4; ++i) {
        int px = mf * 16 + 4 * g + i;
        int pixel = y * 128 + x0 + px;
        h1pre[(((b << 14) + pixel) << 8) + col] = f2bf(acc[mf][nf][i] + bias);
      }
  }
}

// ---------------------------------------------------------------- fused per-query MLP v6
// 256 thr / 4 waves, 2 tiles x 64 rows (32 queries) per block, 3750 blocks.
// Operand-swapped MFMA; XOR-swizzled Xl (row 512B, slot^=(row&7)); wr-table in regs.
__global__ __launch_bounds__(256, 2) void mlp_kernel(
    const float* __restrict__ coord, const float* __restrict__ cell,
    const u16* __restrict__ h1pre,
    const u16* __restrict__ w2t, const u16* __restrict__ w3t, const u16* __restrict__ w4t,
    const float* __restrict__ w1, const float* __restrict__ b2, const float* __restrict__ b3,
    const float* __restrict__ b4, const float* __restrict__ w5, const float* __restrict__ b5,
    float* __restrict__ out) {
  __shared__ short Xl[2][64 * 256];  // [tile][row*256 + swizzled], rows 512B
  __shared__ float relv[128][4];
  __shared__ float area_l[128];
  __shared__ int   idx_l[128];       // (b<<14) + pixel
  __shared__ float predp[4][128];

  int tid = threadIdx.x;
  int lane = tid & 63, wave = tid >> 6;
  int g = lane >> 4, l15 = lane & 15;
  int wc0 = wave * 64;
  int xr = l15 & 7;                  // row-XOR for frag rows (row = mf*16+l15)
  int bid = blockIdx.x;              // 3750 blocks x 32 queries

  // ---- wr rel-weight table -> registers (each thread owns cols c16*8..c16*8+7)
  int c16 = tid & 31;
  float wrr[4][8];
  {
    const float* wr = w1 + 576 * 256;   // [4][256] fp32
    #pragma unroll
    for (int a = 0; a < 4; ++a) {
      f32x4 u0 = *(const f32x4*)(wr + a * 256 + c16 * 8);
      f32x4 u1 = *(const f32x4*)(wr + a * 256 + c16 * 8 + 4);
      #pragma unroll
      for (int e = 0; e < 4; ++e) { wrr[a][e] = u0[e]; wrr[a][4 + e] = u1[e]; }
    }
  }

  // ---- geometry for all 128 rows
  if (tid < 128) {
    int t = tid >> 2, br = tid & 3;            // branch order: vx outer, vy inner
    int gq = bid * 32 + t;
    int b = gq / 30000;
    float c0 = coord[gq * 2 + 0];
    float c1 = coord[gq * 2 + 1];
    float ce0 = cell[gq * 2 + 0];
    float ce1 = cell[gq * 2 + 1];
    float vx = (br & 2) ? 1.0f : -1.0f;
    float vy = (br & 1) ? 1.0f : -1.0f;
    float s0 = c0 + vx * (1.0f / 128.0f) + 1e-6f;
    float s1 = c1 + vy * (1.0f / 128.0f) + 1e-6f;
    s0 = fminf(fmaxf(s0, -1.0f + 1e-6f), 1.0f - 1e-6f);
    s1 = fminf(fmaxf(s1, -1.0f + 1e-6f), 1.0f - 1e-6f);
    float fi = rintf((s0 + 1.0f) * 64.0f - 0.5f);
    float fj = rintf((s1 + 1.0f) * 64.0f - 0.5f);
    fi = fminf(fmaxf(fi, 0.0f), 127.0f);
    fj = fminf(fmaxf(fj, 0.0f), 127.0f);
    float qy = -1.0f + (2.0f * fi + 1.0f) / 128.0f;
    float qx = -1.0f + (2.0f * fj + 1.0f) / 128.0f;
    float rel0 = (c0 - qy) * 128.0f;
    float rel1 = (c1 - qx) * 128.0f;
    idx_l[tid] = (b << 14) + (int)fi * 128 + (int)fj;
    relv[tid][0] = rel0;
    relv[tid][1] = rel1;
    relv[tid][2] = ce0 * 128.0f;
    relv[tid][3] = ce1 * 128.0f;
    area_l[tid] = fabsf(rel0 * rel1) + 1e-9f;
  }
  __syncthreads();

  // ---- gather: per tile one batch of 8x16B loads -> process -> swizzled Xl[t]
  #pragma unroll
  for (int t = 0; t < 2; ++t) {
    short8 v[8];
    #pragma unroll
    for (int it = 0; it < 8; ++it) {
      int rl = it * 8 + (tid >> 5);
      v[it] = *(const short8*)(h1pre + ((size_t)idx_l[t * 64 + rl] << 8) + c16 * 8);
    }
    __builtin_amdgcn_sched_barrier(0);  // keep the 8 loads batched
    #pragma unroll
    for (int it = 0; it < 8; ++it) {
      int rl = it * 8 + (tid >> 5);
      int row = t * 64 + rl;
      float r0 = relv[row][0], r1 = relv[row][1], r2 = relv[row][2], r3 = relv[row][3];
      short8 xo;
      #pragma unroll
      for (int e = 0; e < 8; ++e) {
        float val = bf2f((u16)v[it][e]) + r0 * wrr[0][e] + r1 * wrr[1][e] +
                    r2 * wrr[2][e] + r3 * wrr[3][e];
        xo[e] = (short)bfbits(fmaxf(val, 0.0f));
      }
      *(short8*)(&Xl[t][rl * 256 + ((c16 ^ (rl & 7)) * 8)]) = xo;
    }
  }
  __syncthreads();

  const u16* Wgs[3] = {w2t, w3t, w4t};
  const float* Bgs[3] = {b2, b3, b4};

  #pragma unroll
  for (int layer = 0; layer < 3; ++layer) {
    const u16* Wg = Wgs[layer];
    const float* bias = Bgs[layer];

    // one batched weight preload per layer (serves both tiles)
    bf16x8 breg[32];
    #pragma unroll
    for (int ks = 0; ks < 8; ++ks)
      #pragma unroll
      for (int nf = 0; nf < 4; ++nf)
        breg[ks * 4 + nf] =
            *(const bf16x8*)(Wg + (wc0 + nf * 16 + l15) * 256 + ks * 32 + g * 8);
    __builtin_amdgcn_sched_barrier(0);

    #pragma unroll
    for (int t = 0; t < 2; ++t) {
      f32x4 acc[4][4];
      #pragma unroll
      for (int mf = 0; mf < 4; ++mf)
        #pragma unroll
        for (int nf = 0; nf < 4; ++nf) acc[mf][nf] = (f32x4){0.f, 0.f, 0.f, 0.f};

      #pragma unroll
      for (int ks = 0; ks < 8; ++ks) {
        bf16x8 a[4];
        #pragma unroll
        for (int mf = 0; mf < 4; ++mf)
          a[mf] = *(const bf16x8*)(&Xl[t][(mf * 16 + l15) * 256 + (((ks * 4 + g) ^ xr) * 8)]);
        #pragma unroll
        for (int nf = 0; nf < 4; ++nf)
          #pragma unroll
          for (int mf = 0; mf < 4; ++mf)
            acc[mf][nf] = __builtin_amdgcn_mfma_f32_16x16x32_bf16(
                breg[ks * 4 + nf], a[mf], acc[mf][nf], 0, 0, 0);  // D[row=o][col=q]
      }

      __syncthreads();   // all waves done READING Xl[t] before overwrite
      if (layer < 2) {
        #pragma unroll
        for (int nf = 0; nf < 4; ++nf) {
          int o0 = wc0 + nf * 16 + 4 * g;           // 4 consecutive hidden units
          f32x4 bv = *(const f32x4*)(bias + o0);
          #pragma unroll
          for (int mf = 0; mf < 4; ++mf) {
            u16 p0 = bfbits(fmaxf(acc[mf][nf][0] + bv[0], 0.0f));
            u16 p1 = bfbits(fmaxf(acc[mf][nf][1] + bv[1], 0.0f));
            u16 p2 = bfbits(fmaxf(acc[mf][nf][2] + bv[2], 0.0f));
            u16 p3 = bfbits(fmaxf(acc[mf][nf][3] + bv[3], 0.0f));
            unsigned long long w =
                (unsigned long long)(p0 | ((uint32_t)p1 << 16)) |
                ((unsigned long long)(p2 | ((uint32_t)p3 << 16)) << 32);
            int idx = (mf * 16 + l15) * 256 + (((o0 >> 3) ^ xr) * 8) + (o0 & 7);
            *(unsigned long long*)(&Xl[t][idx]) = w;
          }
        }
      } else {
        // head: relu(acc+b4) dot w5; reduce over o: in-lane (nf,i) + shfl over g
        float s[4] = {0.f, 0.f, 0.f, 0.f};
        #pragma unroll
        for (int nf = 0; nf < 4; ++nf) {
          int o0 = wc0 + nf * 16 + 4 * g;
          f32x4 bv = *(const f32x4*)(b4 + o0);
          f32x4 wv = *(const f32x4*)(w5 + o0);
          #pragma unroll
          for (int mf = 0; mf < 4; ++mf)
            #pragma unroll
            for (int i = 0; i < 4; ++i)
              s[mf] += fmaxf(acc[mf][nf][i] + bv[i], 0.0f) * wv[i];
        }
        #pragma unroll
        for (int mf = 0; mf < 4; ++mf) {
          s[mf] += __shfl_xor(s[mf], 16, 64);
          s[mf] += __shfl_xor(s[mf], 32, 64);
        }
        if (lane < 16) {
          #pragma unroll
          for (int mf = 0; mf < 4; ++mf)
            predp[wave][t * 64 + mf * 16 + lane] = s[mf];
        }
      }
    }
    __syncthreads();   // epi writes visible before next layer / ensemble
  }

  // ---- local ensemble (areas diagonally swapped)
  if (tid < 32) {
    int gq = bid * 32 + tid;
    float pr[4], ar[4];
    #pragma unroll
    for (int br = 0; br < 4; ++br) {
      int r = tid * 4 + br;
      pr[br] = predp[0][r] + predp[1][r] + predp[2][r] + predp[3][r] + b5[0];
      ar[br] = area_l[r];
    }
    float tot = ar[0] + ar[1] + ar[2] + ar[3];
    float ret = 0.0f;
    #pragma unroll
    for (int br = 0; br < 4; ++br) ret += pr[br] * (ar[3 - br] / tot);
    out[gq] = ret;
  }
}

// ---------------------------------------------------------------- launch
extern "C" void kernel_launch(void* const* d_in, const int* in_sizes, int n_in,
                              void* d_out, int out_size, void* d_ws, size_t ws_size,
                              hipStream_t stream) {
  const float* inp    = (const float*)d_in[0];
  const float* coord  = (const float*)d_in[1];
  const float* cell   = (const float*)d_in[2];
  const float* conv_w = (const float*)d_in[3];
  const float* conv_b = (const float*)d_in[4];
  const float* w1 = (const float*)d_in[5];
  const float* b1 = (const float*)d_in[6];
  const float* w2 = (const float*)d_in[7];
  const float* b2 = (const float*)d_in[8];
  const float* w3 = (const float*)d_in[9];
  const float* b3 = (const float*)d_in[10];
  const float* w4 = (const float*)d_in[11];
  const float* b4 = (const float*)d_in[12];
  const float* w5 = (const float*)d_in[13];
  const float* b5 = (const float*)d_in[14];
  float* out = (float*)d_out;

  char* ws = (char*)d_ws;
  u16* feat  = (u16*)(ws);
  u16* h1pre = (u16*)(ws + 8388608);
  u16* w1pt  = (u16*)(ws + 41943040);
  u16* w2t   = (u16*)(ws + 42237952);
  u16* w3t   = (u16*)(ws + 42369024);
  u16* w4t   = (u16*)(ws + 42500096);

  hipLaunchKernelGGL(prep_weights, dim3(1344), dim3(256), 0, stream,
                     w1, w2, w3, w4, w1pt, w2t, w3t, w4t);
  hipLaunchKernelGGL(conv1_kernel, dim3(16384), dim3(256), 0, stream,
                     inp, conv_w, conv_b, feat);
  hipLaunchKernelGGL(layer1_kernel, dim3(1024), dim3(256), 0, stream,
                     feat, w1pt, b1, h1pre);
  hipLaunchKernelGGL(mlp_kernel, dim3(3750), dim3(256), 0, stream,
                     coord, cell, h1pre, w2t, w3t, w4t, w1, b2, b3, b4, w5, b5, out);
}